// Round 1
// baseline (1256.278 us; speedup 1.0000x reference)
//
#include <hip/hip_runtime.h>

typedef __bf16 bf16x8 __attribute__((ext_vector_type(8)));
typedef float f32x4 __attribute__((ext_vector_type(4)));

// Problem constants
// x: [T=4][B=8][C1=64][H=128][W=128] fp32
// conv_w: [C2=128][C1=64][3][3] fp32, gamma/beta: [128]
// out: [T][B][C2=128][H][W] fp32 == [n=T*B][c2][h][w]
#define TBCHW_PLANE 8388608      // B*C1*H*W = 8*64*128*128 (elems per t)
#define NPIX 524288.0f           // N*H*W = 32*128*128

// ---------------- K0: weight repack to MFMA A-fragment order ----------------
// k ordering: k = tap*64 + c  (tap = kh*3+kw). Chunk kc (32 k's) => tap=kc>>1,
// c base=(kc&1)*32. Layout: wf[((kc*8+mtile)*64+lane)*8 + j], lane: m=lane&15,
// k_off=(lane>>4)*8+j  (A[m][k] per-lane fragment for mfma_f32_16x16x32_bf16).
__global__ __launch_bounds__(256) void prep_w(const float* __restrict__ w,
                                              __bf16* __restrict__ wf) {
    int o = blockIdx.x * 256 + threadIdx.x;
    if (o >= 73728) return;
    int j = o & 7;
    int lane = (o >> 3) & 63;
    int mtile = (o >> 9) & 7;
    int kc = o >> 12;
    int k = kc * 32 + (lane >> 4) * 8 + j;
    int c2 = mtile * 16 + (lane & 15);
    int tap = k >> 6, c = k & 63;
    int kh = tap / 3, kw = tap % 3;
    wf[o] = (__bf16)w[((c2 * 64 + c) * 3 + kh) * 3 + kw];
}

// ---------------- K1: LIF recurrence, fp32 exact, write s[n][h][w][c] bf16 ----
__device__ __forceinline__ float lif_step(float& mem, float sp, float xv) {
    // (mem - sp*0.5)*0.25 + xv : sp*0.5 and *0.25 are exact pow2 ops, so any
    // FMA contraction is bitwise-identical to the two-op IEEE sequence.
    mem = (mem - sp * 0.5f) * 0.25f + xv;
    return rintf(fminf(fmaxf(mem, 0.0f), 1.0f));   // round-half-even
}

__global__ __launch_bounds__(256) void lif_kernel(const float* __restrict__ x,
                                                  __bf16* __restrict__ s,
                                                  float* __restrict__ stats) {
    __shared__ __bf16 lds[2 * 128 * 72];  // [t2][w][c pad 72] (144B stride)
    int b = blockIdx.x >> 7, h = blockIdx.x & 127;
    int tid = threadIdx.x;
    if (blockIdx.x == 0) stats[tid] = 0.0f;   // zero 256 stat floats for K2

    float4 mem[8], sp[8];
#pragma unroll
    for (int i = 0; i < 8; ++i) { mem[i] = make_float4(0,0,0,0); sp[i] = make_float4(0,0,0,0); }

    for (int half = 0; half < 2; ++half) {
        if (half) __syncthreads();   // previous write-out done before LDS reuse
#pragma unroll
        for (int t2 = 0; t2 < 2; ++t2) {
            int t = half * 2 + t2;
#pragma unroll
            for (int i = 0; i < 8; ++i) {
                int p = tid + 256 * i;          // [0,2048): c=p>>5, w0=(p&31)*4
                int c = p >> 5, w0 = (p & 31) * 4;
                const float4 xv = *(const float4*)(x + (size_t)t * TBCHW_PLANE +
                                   (((size_t)b * 64 + c) * 128 + h) * 128 + w0);
                float s0 = lif_step(mem[i].x, sp[i].x, xv.x);
                float s1 = lif_step(mem[i].y, sp[i].y, xv.y);
                float s2 = lif_step(mem[i].z, sp[i].z, xv.z);
                float s3 = lif_step(mem[i].w, sp[i].w, xv.w);
                sp[i] = make_float4(s0, s1, s2, s3);
                __bf16* dst = &lds[(t2 * 128 + w0) * 72 + c];
                dst[0] = (__bf16)s0; dst[72] = (__bf16)s1;
                dst[144] = (__bf16)s2; dst[216] = (__bf16)s3;
            }
        }
        __syncthreads();
        // write-out: contiguous 16B chunks over [w][c] per (t,h)
#pragma unroll
        for (int i = 0; i < 8; ++i) {
            int u = tid + 256 * i;              // [0,2048)
            int t2 = u >> 10, inner = u & 1023;
            int w = inner >> 3, c8 = inner & 7;
            bf16x8 v = *(const bf16x8*)&lds[(t2 * 128 + w) * 72 + c8 * 8];
            int n = (half * 2 + t2) * 8 + b;
            *(bf16x8*)(s + (((size_t)n * 128 + h) * 128 + w) * 64 + c8 * 8) = v;
        }
    }
}

// ---------------- K2: implicit-GEMM conv via bf16 MFMA + stat accumulation ---
// Block = one (n, h): full C2=128 x W=128 tile, K=576 staged once in LDS.
__global__ __launch_bounds__(256) void conv_kernel(const __bf16* __restrict__ s,
                                                   const __bf16* __restrict__ wf,
                                                   float* __restrict__ out,
                                                   float* __restrict__ stats) {
    __shared__ __bf16 sb[3 * 130 * 72];   // [row][wl 0..129][c pad 72] 56160 B
    int n = blockIdx.x >> 7, h = blockIdx.x & 127;
    int tid = threadIdx.x;

    // stage rows h-1..h+1 (each 128w x 64c bf16 = 16KB contiguous in s)
#pragma unroll
    for (int i = 0; i < 12; ++i) {
        int u = tid + 256 * i;            // [0,3072)
        int row = u >> 10;                // wave-uniform (64 | 1024)
        int inner = u & 1023;             // w = inner>>3, c8 = inner&7
        int hh = h + row - 1;
        int w = inner >> 3, c8 = inner & 7;
        bf16x8 v;
        if (hh >= 0 && hh < 128) {
            v = *(const bf16x8*)(s + (((size_t)n * 128 + hh) * 128) * 64 + inner * 8);
        } else {
#pragma unroll
            for (int z = 0; z < 8; ++z) v[z] = (__bf16)0.0f;
        }
        *(bf16x8*)&sb[(row * 130 + (w + 1)) * 72 + c8 * 8] = v;
    }
    if (tid < 48) {   // zero halo columns wl=0 and wl=129
        int row = tid / 16, q16 = tid % 16;
        int wl = (q16 & 1) ? 129 : 0, c8 = q16 >> 1;
        bf16x8 z;
#pragma unroll
        for (int e = 0; e < 8; ++e) z[e] = (__bf16)0.0f;
        *(bf16x8*)&sb[(row * 130 + wl) * 72 + c8 * 8] = z;
    }
    __syncthreads();   // the ONLY barrier — LDS is read-only below

    int lane = tid & 63, wave = tid >> 6;
    int wm = wave >> 1, wn = wave & 1;    // 2x2 wave grid, 64x64 each
    int lm = lane & 15, q = lane >> 4;

    f32x4 acc[4][4];
#pragma unroll
    for (int i = 0; i < 4; ++i)
#pragma unroll
        for (int j = 0; j < 4; ++j)
#pragma unroll
            for (int e = 0; e < 4; ++e) acc[i][j][e] = 0.0f;

#pragma unroll
    for (int kc = 0; kc < 18; ++kc) {
        int tap = kc >> 1;
        int kh = tap / 3, kw = tap % 3;   // folds at compile time (unrolled)
        int cb = (kc & 1) * 32;
        bf16x8 a[4], bb[4];
#pragma unroll
        for (int i = 0; i < 4; ++i)
            a[i] = *(const bf16x8*)(wf + (((size_t)kc * 8 + wm * 4 + i) * 64 + lane) * 8);
#pragma unroll
        for (int j = 0; j < 4; ++j) {
            int wl = wn * 64 + j * 16 + lm + kw;   // (w_out + kw - 1) + 1
            bb[j] = *(const bf16x8*)&sb[(kh * 130 + wl) * 72 + cb + q * 8];
        }
#pragma unroll
        for (int i = 0; i < 4; ++i)
#pragma unroll
            for (int j = 0; j < 4; ++j)
                acc[i][j] = __builtin_amdgcn_mfma_f32_16x16x32_bf16(a[i], bb[j], acc[i][j], 0, 0, 0);
    }

    // epilogue: D[m = q*4+r][nn = lane&15]; store fp32 + per-channel stats
#pragma unroll
    for (int i = 0; i < 4; ++i) {
#pragma unroll
        for (int r = 0; r < 4; ++r) {
            int c2 = wm * 64 + i * 16 + q * 4 + r;
            size_t ob = ((size_t)(n * 128 + c2) * 128 + h) * 128 + wn * 64 + lm;
            float sum = 0.0f, ssq = 0.0f;
#pragma unroll
            for (int j = 0; j < 4; ++j) {
                float v = acc[i][j][r];
                out[ob + j * 16] = v;
                sum += v; ssq += v * v;
            }
            // reduce over the 16 lanes sharing q (validity of lane 0 closure ok)
#pragma unroll
            for (int d = 8; d > 0; d >>= 1) {
                sum += __shfl_down(sum, d);
                ssq += __shfl_down(ssq, d);
            }
            if (lm == 0) {
                atomicAdd(&stats[c2], sum);
                atomicAdd(&stats[128 + c2], ssq);
            }
        }
    }
}

// ---------------- K2b: finalize scale/shift --------------------------------
__global__ void finalize_stats(const float* __restrict__ stats,
                               const float* __restrict__ gamma,
                               const float* __restrict__ beta,
                               float* __restrict__ ss) {
    int c = threadIdx.x;
    if (c < 128) {
        const float inv = 1.0f / NPIX;
        float mean = stats[c] * inv;
        float var = stats[128 + c] * inv - mean * mean;
        float sc = gamma[c] * rsqrtf(var + 1e-5f);
        ss[c] = sc;
        ss[128 + c] = beta[c] - mean * sc;
    }
}

// ---------------- K3: in-place BN apply (float4) ----------------------------
__global__ __launch_bounds__(256) void bn_apply(float* __restrict__ out,
                                                const float* __restrict__ ss) {
    size_t i4 = (size_t)blockIdx.x * 256 + threadIdx.x;   // 16777216 float4s
    int c2 = (int)((i4 >> 12) & 127);
    float sc = ss[c2], sh = ss[128 + c2];
    float4* p = (float4*)out + i4;
    float4 v = *p;
    v.x = v.x * sc + sh; v.y = v.y * sc + sh;
    v.z = v.z * sc + sh; v.w = v.w * sc + sh;
    *p = v;
}

extern "C" void kernel_launch(void* const* d_in, const int* in_sizes, int n_in,
                              void* d_out, int out_size, void* d_ws, size_t ws_size,
                              hipStream_t stream) {
    const float* x     = (const float*)d_in[0];
    const float* cw    = (const float*)d_in[1];
    const float* gamma = (const float*)d_in[2];
    const float* beta  = (const float*)d_in[3];
    float* out = (float*)d_out;

    char* ws = (char*)d_ws;
    __bf16* s     = (__bf16*)ws;                           // 67108864 B
    __bf16* wfrag = (__bf16*)(ws + 67108864);              // 147456 B
    float*  stats = (float*)(ws + 67108864 + 147456);      // 256 floats
    float*  ss    = stats + 256;                           // 256 floats

    prep_w        <<<288,   256, 0, stream>>>(cw, wfrag);
    lif_kernel    <<<1024,  256, 0, stream>>>(x, s, stats);   // also zeroes stats
    conv_kernel   <<<4096,  256, 0, stream>>>(s, wfrag, out, stats);
    finalize_stats<<<1,     128, 0, stream>>>(stats, gamma, beta, ss);
    bn_apply      <<<65536, 256, 0, stream>>>(out, ss);
}

// Round 2
// 583.456 us; speedup vs baseline: 2.1532x; 2.1532x over previous
//
#include <hip/hip_runtime.h>

typedef __bf16 bf16x8 __attribute__((ext_vector_type(8)));
typedef float f32x4 __attribute__((ext_vector_type(4)));

// Problem constants
// x: [T=4][B=8][C1=64][H=128][W=128] fp32
// conv_w: [C2=128][C1=64][3][3] fp32, gamma/beta: [128]
// out: [T][B][C2=128][H][W] fp32 == [n=T*B][c2][h][w]
#define TBCHW_PLANE 8388608      // B*C1*H*W = 8*64*128*128 (elems per t)
#define NPIX 524288.0f           // N*H*W = 32*128*128
#define NBLK 4096                // conv grid size (one block per (n,h))

// ---------------- K0: weight repack to MFMA A-fragment order ----------------
// k ordering: k = tap*64 + c  (tap = kh*3+kw). Chunk kc (32 k's) => tap=kc>>1,
// c base=(kc&1)*32. Layout: wf[((kc*8+mtile)*64+lane)*8 + j], lane: m=lane&15,
// k_off=(lane>>4)*8+j  (A[m][k] per-lane fragment for mfma_f32_16x16x32_bf16).
__global__ __launch_bounds__(256) void prep_w(const float* __restrict__ w,
                                              __bf16* __restrict__ wf) {
    int o = blockIdx.x * 256 + threadIdx.x;
    if (o >= 73728) return;
    int j = o & 7;
    int lane = (o >> 3) & 63;
    int mtile = (o >> 9) & 7;
    int kc = o >> 12;
    int k = kc * 32 + (lane >> 4) * 8 + j;
    int c2 = mtile * 16 + (lane & 15);
    int tap = k >> 6, c = k & 63;
    int kh = tap / 3, kw = tap % 3;
    wf[o] = (__bf16)w[((c2 * 64 + c) * 3 + kh) * 3 + kw];
}

// ---------------- K1: LIF recurrence, fp32 exact, write s[n][h][w][c] bf16 ----
__device__ __forceinline__ float lif_step(float& mem, float sp, float xv) {
    // (mem - sp*0.5)*0.25 + xv : sp*0.5 and *0.25 are exact pow2 ops, so any
    // FMA contraction is bitwise-identical to the two-op IEEE sequence.
    mem = (mem - sp * 0.5f) * 0.25f + xv;
    return rintf(fminf(fmaxf(mem, 0.0f), 1.0f));   // round-half-even
}

__global__ __launch_bounds__(256) void lif_kernel(const float* __restrict__ x,
                                                  __bf16* __restrict__ s) {
    __shared__ __bf16 lds[2 * 128 * 72];  // [t2][w][c pad 72] (144B stride)
    int b = blockIdx.x >> 7, h = blockIdx.x & 127;
    int tid = threadIdx.x;

    float4 mem[8], sp[8];
#pragma unroll
    for (int i = 0; i < 8; ++i) { mem[i] = make_float4(0,0,0,0); sp[i] = make_float4(0,0,0,0); }

    for (int half = 0; half < 2; ++half) {
        if (half) __syncthreads();   // previous write-out done before LDS reuse
#pragma unroll
        for (int t2 = 0; t2 < 2; ++t2) {
            int t = half * 2 + t2;
#pragma unroll
            for (int i = 0; i < 8; ++i) {
                int p = tid + 256 * i;          // [0,2048): c=p>>5, w0=(p&31)*4
                int c = p >> 5, w0 = (p & 31) * 4;
                const float4 xv = *(const float4*)(x + (size_t)t * TBCHW_PLANE +
                                   (((size_t)b * 64 + c) * 128 + h) * 128 + w0);
                float s0 = lif_step(mem[i].x, sp[i].x, xv.x);
                float s1 = lif_step(mem[i].y, sp[i].y, xv.y);
                float s2 = lif_step(mem[i].z, sp[i].z, xv.z);
                float s3 = lif_step(mem[i].w, sp[i].w, xv.w);
                sp[i] = make_float4(s0, s1, s2, s3);
                __bf16* dst = &lds[(t2 * 128 + w0) * 72 + c];
                dst[0] = (__bf16)s0; dst[72] = (__bf16)s1;
                dst[144] = (__bf16)s2; dst[216] = (__bf16)s3;
            }
        }
        __syncthreads();
        // write-out: contiguous 16B chunks over [w][c] per (t,h)
#pragma unroll
        for (int i = 0; i < 8; ++i) {
            int u = tid + 256 * i;              // [0,2048)
            int t2 = u >> 10, inner = u & 1023;
            int w = inner >> 3, c8 = inner & 7;
            bf16x8 v = *(const bf16x8*)&lds[(t2 * 128 + w) * 72 + c8 * 8];
            int n = (half * 2 + t2) * 8 + b;
            *(bf16x8*)(s + (((size_t)n * 128 + h) * 128 + w) * 64 + c8 * 8) = v;
        }
    }
}

// ---------------- K2: implicit-GEMM conv via bf16 MFMA + stat partials -------
// Block = one (n, h): full C2=128 x W=128 tile, K=576 staged once in LDS.
// Stats: shfl-reduce -> per-wave LDS partials -> per-block row in `part`
// ([256][NBLK], row = stat*128+c2) -- ZERO global atomics.
__global__ __launch_bounds__(256) void conv_kernel(const __bf16* __restrict__ s,
                                                   const __bf16* __restrict__ wf,
                                                   float* __restrict__ out,
                                                   float* __restrict__ part) {
    __shared__ __align__(16) __bf16 sb[3 * 130 * 72];  // [row][wl 0..129][c pad 72] 56160 B
    int n = blockIdx.x >> 7, h = blockIdx.x & 127;
    int tid = threadIdx.x;

    // stage rows h-1..h+1 (each 128w x 64c bf16 = 16KB contiguous in s)
#pragma unroll
    for (int i = 0; i < 12; ++i) {
        int u = tid + 256 * i;            // [0,3072)
        int row = u >> 10;                // wave-uniform (64 | 1024)
        int inner = u & 1023;             // w = inner>>3, c8 = inner&7
        int hh = h + row - 1;
        int w = inner >> 3, c8 = inner & 7;
        bf16x8 v;
        if (hh >= 0 && hh < 128) {
            v = *(const bf16x8*)(s + (((size_t)n * 128 + hh) * 128) * 64 + inner * 8);
        } else {
#pragma unroll
            for (int z = 0; z < 8; ++z) v[z] = (__bf16)0.0f;
        }
        *(bf16x8*)&sb[(row * 130 + (w + 1)) * 72 + c8 * 8] = v;
    }
    if (tid < 48) {   // zero halo columns wl=0 and wl=129
        int row = tid / 16, q16 = tid % 16;
        int wl = (q16 & 1) ? 129 : 0, c8 = q16 >> 1;
        bf16x8 z;
#pragma unroll
        for (int e = 0; e < 8; ++e) z[e] = (__bf16)0.0f;
        *(bf16x8*)&sb[(row * 130 + wl) * 72 + c8 * 8] = z;
    }
    __syncthreads();   // LDS is read-only during K-loop

    int lane = tid & 63, wave = tid >> 6;
    int wm = wave >> 1, wn = wave & 1;    // 2x2 wave grid, 64x64 each
    int lm = lane & 15, q = lane >> 4;

    f32x4 acc[4][4];
#pragma unroll
    for (int i = 0; i < 4; ++i)
#pragma unroll
        for (int j = 0; j < 4; ++j)
#pragma unroll
            for (int e = 0; e < 4; ++e) acc[i][j][e] = 0.0f;

#pragma unroll
    for (int kc = 0; kc < 18; ++kc) {
        int tap = kc >> 1;
        int kh = tap / 3, kw = tap % 3;   // folds at compile time (unrolled)
        int cb = (kc & 1) * 32;
        bf16x8 a[4], bb[4];
#pragma unroll
        for (int i = 0; i < 4; ++i)
            a[i] = *(const bf16x8*)(wf + (((size_t)kc * 8 + wm * 4 + i) * 64 + lane) * 8);
#pragma unroll
        for (int j = 0; j < 4; ++j) {
            int wl = wn * 64 + j * 16 + lm + kw;   // (w_out + kw - 1) + 1
            bb[j] = *(const bf16x8*)&sb[(kh * 130 + wl) * 72 + cb + q * 8];
        }
#pragma unroll
        for (int i = 0; i < 4; ++i)
#pragma unroll
            for (int j = 0; j < 4; ++j)
                acc[i][j] = __builtin_amdgcn_mfma_f32_16x16x32_bf16(a[i], bb[j], acc[i][j], 0, 0, 0);
    }

    __syncthreads();                       // done reading sb; reuse as float2 P
    float2* P = (float2*)sb;               // P[wave*64 + idx], idx = i*16+q*4+r

    // epilogue: D[m = q*4+r][nn = lane&15]; store fp32 + per-channel partials
#pragma unroll
    for (int i = 0; i < 4; ++i) {
#pragma unroll
        for (int r = 0; r < 4; ++r) {
            int c2 = wm * 64 + i * 16 + q * 4 + r;
            size_t ob = ((size_t)(n * 128 + c2) * 128 + h) * 128 + wn * 64 + lm;
            float sum = 0.0f, ssq = 0.0f;
#pragma unroll
            for (int j = 0; j < 4; ++j) {
                float v = acc[i][j][r];
                out[ob + j * 16] = v;
                sum += v; ssq += v * v;
            }
            // reduce over the 16 lanes sharing q (shifts stay within group)
#pragma unroll
            for (int d = 8; d > 0; d >>= 1) {
                sum += __shfl_down(sum, d);
                ssq += __shfl_down(ssq, d);
            }
            if (lm == 0) {
                // each P slot written exactly once per block (no atomics)
                P[wave * 64 + i * 16 + q * 4 + r] = make_float2(sum, ssq);
            }
        }
    }
    __syncthreads();
    // combine the wave pair sharing wm, write one partial row element
    {
        int stat = tid >> 7, c2x = tid & 127;      // row = stat*128+c2x == tid
        int wp = c2x >> 6, idx = c2x & 63;
        float2 a2 = P[(wp * 2) * 64 + idx];
        float2 b2 = P[(wp * 2 + 1) * 64 + idx];
        float val = stat ? (a2.y + b2.y) : (a2.x + b2.x);
        part[(size_t)tid * NBLK + blockIdx.x] = val;
    }
}

// ---------------- K2b: reduce partials + finalize scale/shift ---------------
// 128 blocks, block c reduces part rows c (sum) and 128+c (ssq), each NBLK long.
__global__ __launch_bounds__(256) void reduce_stats(const float* __restrict__ part,
                                                    const float* __restrict__ gamma,
                                                    const float* __restrict__ beta,
                                                    float* __restrict__ ss) {
    int c = blockIdx.x;
    int tid = threadIdx.x;
    const float* ps = part + (size_t)c * NBLK;
    const float* pq = part + (size_t)(128 + c) * NBLK;
    float sum = 0.0f, ssq = 0.0f;
    for (int i = tid; i < NBLK; i += 256) { sum += ps[i]; ssq += pq[i]; }
#pragma unroll
    for (int d = 32; d > 0; d >>= 1) {
        sum += __shfl_down(sum, d);
        ssq += __shfl_down(ssq, d);
    }
    __shared__ float2 wred[4];
    if ((tid & 63) == 0) wred[tid >> 6] = make_float2(sum, ssq);
    __syncthreads();
    if (tid == 0) {
        float S = 0.0f, Q = 0.0f;
#pragma unroll
        for (int w2 = 0; w2 < 4; ++w2) { S += wred[w2].x; Q += wred[w2].y; }
        const float inv = 1.0f / NPIX;
        float mean = S * inv;
        float var = Q * inv - mean * mean;
        float sc = gamma[c] * rsqrtf(var + 1e-5f);
        ss[c] = sc;
        ss[128 + c] = beta[c] - mean * sc;
    }
}

// ---------------- K3: in-place BN apply (float4) ----------------------------
__global__ __launch_bounds__(256) void bn_apply(float* __restrict__ out,
                                                const float* __restrict__ ss) {
    size_t i4 = (size_t)blockIdx.x * 256 + threadIdx.x;   // 16777216 float4s
    int c2 = (int)((i4 >> 12) & 127);
    float sc = ss[c2], sh = ss[128 + c2];
    float4* p = (float4*)out + i4;
    float4 v = *p;
    v.x = v.x * sc + sh; v.y = v.y * sc + sh;
    v.z = v.z * sc + sh; v.w = v.w * sc + sh;
    *p = v;
}

extern "C" void kernel_launch(void* const* d_in, const int* in_sizes, int n_in,
                              void* d_out, int out_size, void* d_ws, size_t ws_size,
                              hipStream_t stream) {
    const float* x     = (const float*)d_in[0];
    const float* cw    = (const float*)d_in[1];
    const float* gamma = (const float*)d_in[2];
    const float* beta  = (const float*)d_in[3];
    float* out = (float*)d_out;

    char* ws = (char*)d_ws;
    __bf16* s     = (__bf16*)ws;                           // 67108864 B
    __bf16* wfrag = (__bf16*)(ws + 67108864);              // 147456 B
    float*  part  = (float*)(ws + 67108864 + 147456);      // 256*NBLK*4 = 4 MB
    float*  ss    = part + 256 * NBLK;                     // 256 floats

    prep_w      <<<288,   256, 0, stream>>>(cw, wfrag);
    lif_kernel  <<<1024,  256, 0, stream>>>(x, s);
    conv_kernel <<<NBLK,  256, 0, stream>>>(s, wfrag, out, part);
    reduce_stats<<<128,   256, 0, stream>>>(part, gamma, beta, ss);
    bn_apply    <<<65536, 256, 0, stream>>>(out, ss);
}